// Round 1
// baseline (2855.652 us; speedup 1.0000x reference)
//
#include <hip/hip_runtime.h>
#include <hip/hip_bf16.h>

#define D 128            // D_IN == D_OUT == 128
#define D4 32            // D/4 float4s per row

// ---------------------------------------------------------------------------
// Kernel 1: hw[n,:] = (h[n,:] @ W) * norm[n]
// 32-row x 128-col tile per block, 256 threads, 4x4 register blocking.
// W (64 KB) + h-tile (16 KB) in LDS -> 80 KB/block, 2 blocks/CU.
// ---------------------------------------------------------------------------
__global__ __launch_bounds__(256) void gemm_scale_kernel(
    const float* __restrict__ h, const float* __restrict__ W,
    const float* __restrict__ norm, float* __restrict__ hw, int n_nodes)
{
    __shared__ float Ws[D * D];     // W[k][col], row-major
    __shared__ float Hs[32 * D];    // h-tile[r][k]

    const int t = threadIdx.x;
    const int row_base = blockIdx.x * 32;

    // Cooperative load of W: 4096 float4, 16 per thread.
    {
        const float4* W4 = (const float4*)W;
        float4* Ws4 = (float4*)Ws;
        #pragma unroll
        for (int i = 0; i < 16; ++i) Ws4[t + 256 * i] = W4[t + 256 * i];
    }
    // Cooperative load of the 32-row h tile: 1024 float4, 4 per thread.
    {
        const float4* h4 = (const float4*)(h + (long)row_base * D);
        float4* Hs4 = (float4*)Hs;
        #pragma unroll
        for (int i = 0; i < 4; ++i) Hs4[t + 256 * i] = h4[t + 256 * i];
    }
    __syncthreads();

    const int tx = t & 31;          // col group: cols [tx*4, tx*4+4)
    const int ty = t >> 5;          // row group: rows [ty*4, ty*4+4)
    const int col0 = tx * 4;
    const int r0 = ty * 4;

    float acc[4][4] = {};

    #pragma unroll 4
    for (int k = 0; k < D; k += 4) {
        float4 a[4], b[4];
        #pragma unroll
        for (int i = 0; i < 4; ++i)
            a[i] = *(const float4*)&Hs[(r0 + i) * D + k];
        #pragma unroll
        for (int j = 0; j < 4; ++j)
            b[j] = *(const float4*)&Ws[(k + j) * D + col0];
        #pragma unroll
        for (int i = 0; i < 4; ++i) {
            acc[i][0] += a[i].x * b[0].x + a[i].y * b[1].x + a[i].z * b[2].x + a[i].w * b[3].x;
            acc[i][1] += a[i].x * b[0].y + a[i].y * b[1].y + a[i].z * b[2].y + a[i].w * b[3].y;
            acc[i][2] += a[i].x * b[0].z + a[i].y * b[1].z + a[i].z * b[2].z + a[i].w * b[3].z;
            acc[i][3] += a[i].x * b[0].w + a[i].y * b[1].w + a[i].z * b[2].w + a[i].w * b[3].w;
        }
    }

    #pragma unroll
    for (int i = 0; i < 4; ++i) {
        const int row = row_base + r0 + i;
        const float nv = norm[row];
        float4 o;
        o.x = acc[i][0] * nv; o.y = acc[i][1] * nv;
        o.z = acc[i][2] * nv; o.w = acc[i][3] * nv;
        *(float4*)&hw[(long)row * D + col0] = o;
    }
}

// ---------------------------------------------------------------------------
// Kernel 2: scatter-add. One thread handles (edge e, 4-dim group g):
// out[dst[e], g*4 .. g*4+3] += hw[src[e], g*4 .. g*4+3]
// ---------------------------------------------------------------------------
__global__ __launch_bounds__(256) void scatter_kernel(
    const float* __restrict__ hw, const int* __restrict__ src,
    const int* __restrict__ dst, float* __restrict__ out, int n_edges)
{
    const int idx = blockIdx.x * 256 + threadIdx.x;
    if (idx >= n_edges * D4) return;
    const int e = idx >> 5;       // edge
    const int g = idx & 31;       // float4 group within the row
    const int s = src[e];
    const int d = dst[e];
    const float4 v = ((const float4*)hw)[(long)s * D4 + g];
    float* o = out + (long)d * D + g * 4;
    atomicAdd(o + 0, v.x);
    atomicAdd(o + 1, v.y);
    atomicAdd(o + 2, v.z);
    atomicAdd(o + 3, v.w);
}

// ---------------------------------------------------------------------------
// Kernel 3: out = out * norm + bias (in place)
// ---------------------------------------------------------------------------
__global__ __launch_bounds__(256) void finalize_kernel(
    float* __restrict__ out, const float* __restrict__ norm,
    const float* __restrict__ bias, int n_nodes)
{
    const int idx = blockIdx.x * 256 + threadIdx.x;
    if (idx >= n_nodes * D4) return;
    const int n = idx >> 5;
    const int g = idx & 31;
    float4 v = ((float4*)out)[idx];
    const float nv = norm[n];
    const float4 b = ((const float4*)bias)[g];
    v.x = v.x * nv + b.x;
    v.y = v.y * nv + b.y;
    v.z = v.z * nv + b.z;
    v.w = v.w * nv + b.w;
    ((float4*)out)[idx] = v;
}

extern "C" void kernel_launch(void* const* d_in, const int* in_sizes, int n_in,
                              void* d_out, int out_size, void* d_ws, size_t ws_size,
                              hipStream_t stream) {
    const float* h    = (const float*)d_in[0];
    const float* norm = (const float*)d_in[1];
    const int*   src  = (const int*)d_in[2];
    const int*   dst  = (const int*)d_in[3];
    const float* W    = (const float*)d_in[4];
    const float* bias = (const float*)d_in[5];
    float* out = (float*)d_out;

    const int n_nodes = in_sizes[1];       // norm has N elements
    const int n_edges = in_sizes[2];       // src has E elements

    float* hw = (float*)d_ws;              // N*128 floats = 51.2 MB scratch

    // 1) hw = (h @ W) * norm
    gemm_scale_kernel<<<(n_nodes + 31) / 32, 256, 0, stream>>>(h, W, norm, hw, n_nodes);

    // 2) zero output accumulator
    hipMemsetAsync(d_out, 0, (size_t)out_size * sizeof(float), stream);

    // 3) scatter-add messages
    {
        const int work = n_edges * D4;
        scatter_kernel<<<(work + 255) / 256, 256, 0, stream>>>(hw, src, dst, out, n_edges);
    }

    // 4) out = out * norm + bias
    {
        const int work = n_nodes * D4;
        finalize_kernel<<<(work + 255) / 256, 256, 0, stream>>>(out, norm, bias, n_nodes);
    }
}

// Round 2
// 548.306 us; speedup vs baseline: 5.2081x; 5.2081x over previous
//
#include <hip/hip_runtime.h>
#include <hip/hip_bf16.h>

#define D 128            // D_IN == D_OUT == 128
#define D4 32            // D/4 float4s per row

// ---------------------------------------------------------------------------
// Kernel 1: hw[n,:] = (h[n,:] @ W) * norm[n]
// 32-row x 128-col tile per block, 256 threads, 4x4 register blocking.
// ---------------------------------------------------------------------------
__global__ __launch_bounds__(256) void gemm_scale_kernel(
    const float* __restrict__ h, const float* __restrict__ W,
    const float* __restrict__ norm, float* __restrict__ hw, int n_nodes)
{
    __shared__ float Ws[D * D];     // W[k][col], row-major
    __shared__ float Hs[32 * D];    // h-tile[r][k]

    const int t = threadIdx.x;
    const int row_base = blockIdx.x * 32;

    {
        const float4* W4 = (const float4*)W;
        float4* Ws4 = (float4*)Ws;
        #pragma unroll
        for (int i = 0; i < 16; ++i) Ws4[t + 256 * i] = W4[t + 256 * i];
    }
    {
        const float4* h4 = (const float4*)(h + (long)row_base * D);
        float4* Hs4 = (float4*)Hs;
        #pragma unroll
        for (int i = 0; i < 4; ++i) Hs4[t + 256 * i] = h4[t + 256 * i];
    }
    __syncthreads();

    const int tx = t & 31;
    const int ty = t >> 5;
    const int col0 = tx * 4;
    const int r0 = ty * 4;

    float acc[4][4] = {};

    #pragma unroll 4
    for (int k = 0; k < D; k += 4) {
        float4 a[4], b[4];
        #pragma unroll
        for (int i = 0; i < 4; ++i)
            a[i] = *(const float4*)&Hs[(r0 + i) * D + k];
        #pragma unroll
        for (int j = 0; j < 4; ++j)
            b[j] = *(const float4*)&Ws[(k + j) * D + col0];
        #pragma unroll
        for (int i = 0; i < 4; ++i) {
            acc[i][0] += a[i].x * b[0].x + a[i].y * b[1].x + a[i].z * b[2].x + a[i].w * b[3].x;
            acc[i][1] += a[i].x * b[0].y + a[i].y * b[1].y + a[i].z * b[2].y + a[i].w * b[3].y;
            acc[i][2] += a[i].x * b[0].z + a[i].y * b[1].z + a[i].z * b[2].z + a[i].w * b[3].z;
            acc[i][3] += a[i].x * b[0].w + a[i].y * b[1].w + a[i].z * b[2].w + a[i].w * b[3].w;
        }
    }

    #pragma unroll
    for (int i = 0; i < 4; ++i) {
        const int row = row_base + r0 + i;
        const float nv = norm[row];
        float4 o;
        o.x = acc[i][0] * nv; o.y = acc[i][1] * nv;
        o.z = acc[i][2] * nv; o.w = acc[i][3] * nv;
        *(float4*)&hw[(long)row * D + col0] = o;
    }
}

// ---------------------------------------------------------------------------
// CSR build: histogram -> 2-level exclusive scan -> edge permutation
// ---------------------------------------------------------------------------
__global__ __launch_bounds__(256) void hist_kernel(
    const int* __restrict__ dst, int* __restrict__ cnt, int n_edges)
{
    const int e = blockIdx.x * 256 + threadIdx.x;
    if (e < n_edges) atomicAdd(&cnt[dst[e]], 1);
}

// Each block scans 1024 elements (256 threads x 4). Writes block-local
// exclusive scan into off[] and the block total into bsums[blockIdx].
__global__ __launch_bounds__(256) void scan_blocks_kernel(
    const int* __restrict__ cnt, int* __restrict__ off,
    int* __restrict__ bsums, int n)
{
    __shared__ int tmp[256];
    const int t = threadIdx.x;
    const int base = blockIdx.x * 1024 + t * 4;

    int v[4];
    int s = 0;
    #pragma unroll
    for (int k = 0; k < 4; ++k) {
        v[k] = (base + k < n) ? cnt[base + k] : 0;
        s += v[k];
    }
    tmp[t] = s;
    __syncthreads();
    for (int ofs = 1; ofs < 256; ofs <<= 1) {
        int x = (t >= ofs) ? tmp[t - ofs] : 0;
        __syncthreads();
        tmp[t] += x;
        __syncthreads();
    }
    int run = tmp[t] - s;   // exclusive prefix of this thread's group
    #pragma unroll
    for (int k = 0; k < 4; ++k) {
        if (base + k < n) off[base + k] = run;
        run += v[k];
    }
    if (t == 255) bsums[blockIdx.x] = tmp[255];
}

// Single block: exclusive scan of nb (<=128) block sums in place.
__global__ __launch_bounds__(128) void scan_top_kernel(int* __restrict__ bsums, int nb)
{
    __shared__ int tmp[128];
    const int t = threadIdx.x;
    const int orig = (t < nb) ? bsums[t] : 0;
    tmp[t] = orig;
    __syncthreads();
    for (int ofs = 1; ofs < 128; ofs <<= 1) {
        int x = (t >= ofs) ? tmp[t - ofs] : 0;
        __syncthreads();
        tmp[t] += x;
        __syncthreads();
    }
    if (t < nb) bsums[t] = tmp[t] - orig;
}

// off[i] += bsums[block]; cur[i] = off[i]
__global__ __launch_bounds__(256) void scan_add_kernel(
    int* __restrict__ off, int* __restrict__ cur,
    const int* __restrict__ bsums, int n)
{
    const int t = threadIdx.x;
    const int base = blockIdx.x * 1024 + t * 4;
    const int add = bsums[blockIdx.x];
    #pragma unroll
    for (int k = 0; k < 4; ++k) {
        const int i = base + k;
        if (i < n) {
            const int o = off[i] + add;
            off[i] = o;
            cur[i] = o;
        }
    }
}

__global__ __launch_bounds__(256) void fill_kernel(
    const int* __restrict__ src, const int* __restrict__ dst,
    int* __restrict__ cur, int* __restrict__ srcs, int n_edges)
{
    const int e = blockIdx.x * 256 + threadIdx.x;
    if (e >= n_edges) return;
    const int d = dst[e];
    const int pos = atomicAdd(&cur[d], 1);
    srcs[pos] = src[e];
}

// ---------------------------------------------------------------------------
// Aggregation: 2 nodes per 256-thread block; 128 threads per node (one per
// dim, 2 waves). Each wave loads 64 edge indices coalesced, broadcasts via
// __shfl, accumulates coalesced 512B row reads. Fuses out = agg*norm + bias.
// ---------------------------------------------------------------------------
__global__ __launch_bounds__(256) void agg_kernel(
    const float* __restrict__ hw, const int* __restrict__ srcs,
    const int* __restrict__ off, const int* __restrict__ cnt,
    const float* __restrict__ norm, const float* __restrict__ bias,
    float* __restrict__ out, int n_nodes)
{
    const int t = threadIdx.x;
    const int node = blockIdx.x * 2 + (t >> 7);
    if (node >= n_nodes) return;
    const int dim  = t & 127;
    const int lane = t & 63;

    const int start = off[node];
    const int deg   = cnt[node];

    float acc = 0.0f;
    for (int j0 = 0; j0 < deg; j0 += 64) {
        const int rem = deg - j0;
        const int myidx = (lane < rem) ? srcs[start + j0 + lane] : 0;
        const int cnt64 = rem < 64 ? rem : 64;
        for (int jj = 0; jj < cnt64; ++jj) {
            const int s = __shfl(myidx, jj);
            acc += hw[(long)s * D + dim];
        }
    }
    out[(long)node * D + dim] = acc * norm[node] + bias[dim];
}

// ---------------------------------------------------------------------------
// Fallback path (R1): atomic scatter + finalize, used only if ws too small.
// ---------------------------------------------------------------------------
__global__ __launch_bounds__(256) void scatter_kernel(
    const float* __restrict__ hw, const int* __restrict__ src,
    const int* __restrict__ dst, float* __restrict__ out, int n_edges)
{
    const int idx = blockIdx.x * 256 + threadIdx.x;
    if (idx >= n_edges * D4) return;
    const int e = idx >> 5;
    const int g = idx & 31;
    const int s = src[e];
    const int d = dst[e];
    const float4 v = ((const float4*)hw)[(long)s * D4 + g];
    float* o = out + (long)d * D + g * 4;
    atomicAdd(o + 0, v.x);
    atomicAdd(o + 1, v.y);
    atomicAdd(o + 2, v.z);
    atomicAdd(o + 3, v.w);
}

__global__ __launch_bounds__(256) void finalize_kernel(
    float* __restrict__ out, const float* __restrict__ norm,
    const float* __restrict__ bias, int n_nodes)
{
    const int idx = blockIdx.x * 256 + threadIdx.x;
    if (idx >= n_nodes * D4) return;
    const int n = idx >> 5;
    const int g = idx & 31;
    float4 v = ((float4*)out)[idx];
    const float nv = norm[n];
    const float4 b = ((const float4*)bias)[g];
    v.x = v.x * nv + b.x;
    v.y = v.y * nv + b.y;
    v.z = v.z * nv + b.z;
    v.w = v.w * nv + b.w;
    ((float4*)out)[idx] = v;
}

extern "C" void kernel_launch(void* const* d_in, const int* in_sizes, int n_in,
                              void* d_out, int out_size, void* d_ws, size_t ws_size,
                              hipStream_t stream) {
    const float* h    = (const float*)d_in[0];
    const float* norm = (const float*)d_in[1];
    const int*   src  = (const int*)d_in[2];
    const int*   dst  = (const int*)d_in[3];
    const float* W    = (const float*)d_in[4];
    const float* bias = (const float*)d_in[5];
    float* out = (float*)d_out;

    const int n_nodes = in_sizes[1];
    const int n_edges = in_sizes[2];

    // ---- workspace layout (256B aligned) ----
    size_t p = 0;
    auto take = [&](size_t bytes) {
        size_t cur = p;
        p += (bytes + 255) & ~(size_t)255;
        return cur;
    };
    const size_t hw_off    = take((size_t)n_nodes * D * sizeof(float));
    const size_t cnt_off   = take((size_t)n_nodes * sizeof(int));
    const size_t off_off   = take((size_t)n_nodes * sizeof(int));
    const size_t cur_off   = take((size_t)n_nodes * sizeof(int));
    const size_t bsum_off  = take(1024 * sizeof(int));
    const size_t srcs_off  = take((size_t)n_edges * sizeof(int));
    const size_t needed = p;

    char* ws = (char*)d_ws;
    float* hw = (float*)(ws + hw_off);

    const int NB = (n_nodes + 1023) / 1024;   // scan blocks (98 for N=100K)

    // 1) hw = (h @ W) * norm  (pre-aggregation scale baked in)
    gemm_scale_kernel<<<(n_nodes + 31) / 32, 256, 0, stream>>>(h, W, norm, hw, n_nodes);

    if (ws_size >= needed && NB <= 128) {
        // ---- CSR path ----
        int* cnt   = (int*)(ws + cnt_off);
        int* off   = (int*)(ws + off_off);
        int* cur   = (int*)(ws + cur_off);
        int* bsums = (int*)(ws + bsum_off);
        int* srcs  = (int*)(ws + srcs_off);

        hipMemsetAsync(cnt, 0, (size_t)n_nodes * sizeof(int), stream);
        hist_kernel<<<(n_edges + 255) / 256, 256, 0, stream>>>(dst, cnt, n_edges);
        scan_blocks_kernel<<<NB, 256, 0, stream>>>(cnt, off, bsums, n_nodes);
        scan_top_kernel<<<1, 128, 0, stream>>>(bsums, NB);
        scan_add_kernel<<<NB, 256, 0, stream>>>(off, cur, bsums, n_nodes);
        fill_kernel<<<(n_edges + 255) / 256, 256, 0, stream>>>(src, dst, cur, srcs, n_edges);
        agg_kernel<<<(n_nodes + 1) / 2, 256, 0, stream>>>(hw, srcs, off, cnt, norm, bias,
                                                          out, n_nodes);
    } else {
        // ---- fallback: atomic scatter (R1 path) ----
        hipMemsetAsync(d_out, 0, (size_t)out_size * sizeof(float), stream);
        const int work = n_edges * D4;
        scatter_kernel<<<(work + 255) / 256, 256, 0, stream>>>(hw, src, dst, out, n_edges);
        const int work2 = n_nodes * D4;
        finalize_kernel<<<(work2 + 255) / 256, 256, 0, stream>>>(out, norm, bias, n_nodes);
    }
}

// Round 3
// 409.425 us; speedup vs baseline: 6.9748x; 1.3392x over previous
//
#include <hip/hip_runtime.h>
#include <hip/hip_bf16.h>

#define D 128            // D_IN == D_OUT == 128
#define D4 32            // D/4 float4s per row

// float -> bf16 with round-to-nearest-even (bit trick, no NaN concerns here)
static __device__ __forceinline__ unsigned short f2bf(float f) {
    unsigned u = __float_as_uint(f);
    u += 0x7FFFu + ((u >> 16) & 1u);
    return (unsigned short)(u >> 16);
}
static __device__ __forceinline__ float bf2f(unsigned short u) {
    return __uint_as_float(((unsigned)u) << 16);
}

// ---------------------------------------------------------------------------
// Kernel 1: hwb[n,:] = bf16( (h[n,:] @ W) * norm[n] )
// 32-row x 128-col tile per block, 256 threads, 4x4 register blocking.
// ---------------------------------------------------------------------------
__global__ __launch_bounds__(256) void gemm_scale_kernel(
    const float* __restrict__ h, const float* __restrict__ W,
    const float* __restrict__ norm, unsigned short* __restrict__ hwb,
    int n_nodes)
{
    __shared__ float Ws[D * D];     // W[k][col], row-major
    __shared__ float Hs[32 * D];    // h-tile[r][k]

    const int t = threadIdx.x;
    const int row_base = blockIdx.x * 32;

    {
        const float4* W4 = (const float4*)W;
        float4* Ws4 = (float4*)Ws;
        #pragma unroll
        for (int i = 0; i < 16; ++i) Ws4[t + 256 * i] = W4[t + 256 * i];
    }
    {
        const float4* h4 = (const float4*)(h + (long)row_base * D);
        float4* Hs4 = (float4*)Hs;
        #pragma unroll
        for (int i = 0; i < 4; ++i) Hs4[t + 256 * i] = h4[t + 256 * i];
    }
    __syncthreads();

    const int tx = t & 31;
    const int ty = t >> 5;
    const int col0 = tx * 4;
    const int r0 = ty * 4;

    float acc[4][4] = {};

    #pragma unroll 4
    for (int k = 0; k < D; k += 4) {
        float4 a[4], b[4];
        #pragma unroll
        for (int i = 0; i < 4; ++i)
            a[i] = *(const float4*)&Hs[(r0 + i) * D + k];
        #pragma unroll
        for (int j = 0; j < 4; ++j)
            b[j] = *(const float4*)&Ws[(k + j) * D + col0];
        #pragma unroll
        for (int i = 0; i < 4; ++i) {
            acc[i][0] += a[i].x * b[0].x + a[i].y * b[1].x + a[i].z * b[2].x + a[i].w * b[3].x;
            acc[i][1] += a[i].x * b[0].y + a[i].y * b[1].y + a[i].z * b[2].y + a[i].w * b[3].y;
            acc[i][2] += a[i].x * b[0].z + a[i].y * b[1].z + a[i].z * b[2].z + a[i].w * b[3].z;
            acc[i][3] += a[i].x * b[0].w + a[i].y * b[1].w + a[i].z * b[2].w + a[i].w * b[3].w;
        }
    }

    #pragma unroll
    for (int i = 0; i < 4; ++i) {
        const int row = row_base + r0 + i;
        const float nv = norm[row];
        ushort4 o;
        o.x = f2bf(acc[i][0] * nv);
        o.y = f2bf(acc[i][1] * nv);
        o.z = f2bf(acc[i][2] * nv);
        o.w = f2bf(acc[i][3] * nv);
        *(ushort4*)&hwb[(long)row * D + col0] = o;
    }
}

// ---------------------------------------------------------------------------
// srcs_init: fill padded edge array with dummy index n_nodes; zero the dummy
// bf16 row (row n_nodes of hwb).
// ---------------------------------------------------------------------------
__global__ __launch_bounds__(256) void srcs_init_kernel(
    int* __restrict__ srcs, unsigned short* __restrict__ hwb,
    int n_total, int n_nodes)
{
    const int i = blockIdx.x * 256 + threadIdx.x;
    if (i < n_total) srcs[i] = n_nodes;
    if (i < 32) {
        ushort4 z; z.x = z.y = z.z = z.w = 0;
        ((ushort4*)(hwb + (long)n_nodes * D))[i] = z;
    }
}

// ---------------------------------------------------------------------------
// CSR build: histogram -> 2-level exclusive scan (PADDED to x8) -> fill
// ---------------------------------------------------------------------------
__global__ __launch_bounds__(256) void hist_kernel(
    const int* __restrict__ dst, int* __restrict__ cnt, int n_edges)
{
    const int e = blockIdx.x * 256 + threadIdx.x;
    if (e < n_edges) atomicAdd(&cnt[dst[e]], 1);
}

// Block scans 1024 counts (padded to multiples of 8); off gets block-local
// exclusive scan of PADDED counts; bsums gets the block total.
__global__ __launch_bounds__(256) void scan_blocks_kernel(
    const int* __restrict__ cnt, int* __restrict__ off,
    int* __restrict__ bsums, int n)
{
    __shared__ int tmp[256];
    const int t = threadIdx.x;
    const int base = blockIdx.x * 1024 + t * 4;

    int v[4];
    int s = 0;
    #pragma unroll
    for (int k = 0; k < 4; ++k) {
        int c = (base + k < n) ? cnt[base + k] : 0;
        v[k] = (c + 7) & ~7;        // pad each segment to multiple of 8
        s += v[k];
    }
    tmp[t] = s;
    __syncthreads();
    for (int ofs = 1; ofs < 256; ofs <<= 1) {
        int x = (t >= ofs) ? tmp[t - ofs] : 0;
        __syncthreads();
        tmp[t] += x;
        __syncthreads();
    }
    int run = tmp[t] - s;
    #pragma unroll
    for (int k = 0; k < 4; ++k) {
        if (base + k < n) off[base + k] = run;
        run += v[k];
    }
    if (t == 255) bsums[blockIdx.x] = tmp[255];
}

__global__ __launch_bounds__(128) void scan_top_kernel(int* __restrict__ bsums, int nb)
{
    __shared__ int tmp[128];
    const int t = threadIdx.x;
    const int orig = (t < nb) ? bsums[t] : 0;
    tmp[t] = orig;
    __syncthreads();
    for (int ofs = 1; ofs < 128; ofs <<= 1) {
        int x = (t >= ofs) ? tmp[t - ofs] : 0;
        __syncthreads();
        tmp[t] += x;
        __syncthreads();
    }
    if (t < nb) bsums[t] = tmp[t] - orig;
}

__global__ __launch_bounds__(256) void scan_add_kernel(
    int* __restrict__ off, int* __restrict__ cur,
    const int* __restrict__ bsums, int n)
{
    const int t = threadIdx.x;
    const int base = blockIdx.x * 1024 + t * 4;
    const int add = bsums[blockIdx.x];
    #pragma unroll
    for (int k = 0; k < 4; ++k) {
        const int i = base + k;
        if (i < n) {
            const int o = off[i] + add;
            off[i] = o;
            cur[i] = o;
        }
    }
}

__global__ __launch_bounds__(256) void fill_kernel(
    const int* __restrict__ src, const int* __restrict__ dst,
    int* __restrict__ cur, int* __restrict__ srcs, int n_edges)
{
    const int e = blockIdx.x * 256 + threadIdx.x;
    if (e >= n_edges) return;
    const int d = dst[e];
    const int pos = atomicAdd(&cur[d], 1);
    srcs[pos] = src[e];
}

// ---------------------------------------------------------------------------
// Aggregation v2: 8 nodes per 256-thread block, 32 lanes per node, ushort4
// (4 dims, bf16) per lane. Segments padded to x8 -> inner loop is a fully
// unrolled batch of 8 independent 256B row loads (MLP=8). Edge indices are
// fetched 32-at-a-time and broadcast via __shfl within the 32-lane subgroup.
// Fuses out = agg*norm + bias.
// ---------------------------------------------------------------------------
__global__ __launch_bounds__(256) void agg_kernel(
    const unsigned short* __restrict__ hwb, const int* __restrict__ srcs,
    const int* __restrict__ off, const int* __restrict__ cnt,
    const float* __restrict__ norm, const float* __restrict__ bias,
    float* __restrict__ out, int n_nodes)
{
    const int t = threadIdx.x;
    const int sub = t >> 5;          // node slot within block
    const int lane32 = t & 31;       // dim group (4 dims)
    const int node = blockIdx.x * 8 + sub;
    if (node >= n_nodes) return;

    const int start = off[node];
    const int deg = cnt[node];
    const int nb8 = (deg + 7) >> 3;  // padded batch count

    const ushort4* hw4 = (const ushort4*)hwb;   // row = 32 ushort4

    float4 acc; acc.x = acc.y = acc.z = acc.w = 0.0f;
    int myidx = 0;

    for (int b = 0; b < nb8; ++b) {
        const int q = b & 3;
        if (q == 0) myidx = srcs[start + b * 8 + lane32];  // next 32 edges
        ushort4 v[8];
        #pragma unroll
        for (int jj = 0; jj < 8; ++jj) {
            const int s = __shfl(myidx, q * 8 + jj, 32);
            v[jj] = hw4[(long)s * D4 + lane32];
        }
        #pragma unroll
        for (int jj = 0; jj < 8; ++jj) {
            acc.x += bf2f(v[jj].x);
            acc.y += bf2f(v[jj].y);
            acc.z += bf2f(v[jj].z);
            acc.w += bf2f(v[jj].w);
        }
    }

    const float nv = norm[node];
    const float4 bs = ((const float4*)bias)[lane32];
    float4 o;
    o.x = acc.x * nv + bs.x;
    o.y = acc.y * nv + bs.y;
    o.z = acc.z * nv + bs.z;
    o.w = acc.w * nv + bs.w;
    ((float4*)out)[(long)node * D4 + lane32] = o;
}

// ---------------------------------------------------------------------------
// Fallback path: atomic scatter from bf16 hwb + finalize (ws too small).
// ---------------------------------------------------------------------------
__global__ __launch_bounds__(256) void scatter_kernel(
    const unsigned short* __restrict__ hwb, const int* __restrict__ src,
    const int* __restrict__ dst, float* __restrict__ out, int n_edges)
{
    const int idx = blockIdx.x * 256 + threadIdx.x;
    if (idx >= n_edges * D4) return;
    const int e = idx >> 5;
    const int g = idx & 31;
    const int s = src[e];
    const int d = dst[e];
    const ushort4 v = ((const ushort4*)hwb)[(long)s * D4 + g];
    float* o = out + (long)d * D + g * 4;
    atomicAdd(o + 0, bf2f(v.x));
    atomicAdd(o + 1, bf2f(v.y));
    atomicAdd(o + 2, bf2f(v.z));
    atomicAdd(o + 3, bf2f(v.w));
}

__global__ __launch_bounds__(256) void finalize_kernel(
    float* __restrict__ out, const float* __restrict__ norm,
    const float* __restrict__ bias, int n_nodes)
{
    const int idx = blockIdx.x * 256 + threadIdx.x;
    if (idx >= n_nodes * D4) return;
    const int n = idx >> 5;
    const int g = idx & 31;
    float4 v = ((float4*)out)[idx];
    const float nv = norm[n];
    const float4 b = ((const float4*)bias)[g];
    v.x = v.x * nv + b.x;
    v.y = v.y * nv + b.y;
    v.z = v.z * nv + b.z;
    v.w = v.w * nv + b.w;
    ((float4*)out)[idx] = v;
}

extern "C" void kernel_launch(void* const* d_in, const int* in_sizes, int n_in,
                              void* d_out, int out_size, void* d_ws, size_t ws_size,
                              hipStream_t stream) {
    const float* h    = (const float*)d_in[0];
    const float* norm = (const float*)d_in[1];
    const int*   src  = (const int*)d_in[2];
    const int*   dst  = (const int*)d_in[3];
    const float* W    = (const float*)d_in[4];
    const float* bias = (const float*)d_in[5];
    float* out = (float*)d_out;

    const int n_nodes = in_sizes[1];
    const int n_edges = in_sizes[2];

    // padded srcs worst case: every node pads up to +8, plus read slack
    const int srcs_len = n_edges + 8 * n_nodes + 64;

    // ---- workspace layout (256B aligned) ----
    size_t p = 0;
    auto take = [&](size_t bytes) {
        size_t cur = p;
        p += (bytes + 255) & ~(size_t)255;
        return cur;
    };
    const size_t hwb_off   = take(((size_t)n_nodes + 1) * D * sizeof(unsigned short));
    const size_t cnt_off   = take((size_t)n_nodes * sizeof(int));
    const size_t off_off   = take((size_t)n_nodes * sizeof(int));
    const size_t cur_off   = take((size_t)n_nodes * sizeof(int));
    const size_t bsum_off  = take(1024 * sizeof(int));
    const size_t srcs_off  = take((size_t)srcs_len * sizeof(int));
    const size_t needed = p;

    char* ws = (char*)d_ws;
    unsigned short* hwb = (unsigned short*)(ws + hwb_off);

    const int NB = (n_nodes + 1023) / 1024;   // 98 for N=100K

    // 1) hwb = bf16((h @ W) * norm)
    gemm_scale_kernel<<<(n_nodes + 31) / 32, 256, 0, stream>>>(h, W, norm, hwb, n_nodes);

    if (ws_size >= needed && NB <= 128) {
        int* cnt   = (int*)(ws + cnt_off);
        int* off   = (int*)(ws + off_off);
        int* cur   = (int*)(ws + cur_off);
        int* bsums = (int*)(ws + bsum_off);
        int* srcs  = (int*)(ws + srcs_off);

        srcs_init_kernel<<<(srcs_len + 255) / 256, 256, 0, stream>>>(srcs, hwb, srcs_len, n_nodes);
        hipMemsetAsync(cnt, 0, (size_t)n_nodes * sizeof(int), stream);
        hist_kernel<<<(n_edges + 255) / 256, 256, 0, stream>>>(dst, cnt, n_edges);
        scan_blocks_kernel<<<NB, 256, 0, stream>>>(cnt, off, bsums, n_nodes);
        scan_top_kernel<<<1, 128, 0, stream>>>(bsums, NB);
        scan_add_kernel<<<NB, 256, 0, stream>>>(off, cur, bsums, n_nodes);
        fill_kernel<<<(n_edges + 255) / 256, 256, 0, stream>>>(src, dst, cur, srcs, n_edges);
        agg_kernel<<<(n_nodes + 7) / 8, 256, 0, stream>>>(hwb, srcs, off, cnt, norm, bias,
                                                          out, n_nodes);
    } else {
        hipMemsetAsync(d_out, 0, (size_t)out_size * sizeof(float), stream);
        const int work = n_edges * D4;
        scatter_kernel<<<(work + 255) / 256, 256, 0, stream>>>(hwb, src, dst, out, n_edges);
        const int work2 = n_nodes * D4;
        finalize_kernel<<<(work2 + 255) / 256, 256, 0, stream>>>(out, norm, bias, n_nodes);
    }
}

// Round 4
// 392.573 us; speedup vs baseline: 7.2742x; 1.0429x over previous
//
#include <hip/hip_runtime.h>
#include <hip/hip_bf16.h>

#define D 128            // D_IN == D_OUT == 128
#define D4 32            // D/4 float4s per row

// float -> bf16 with round-to-nearest-even (bit trick, no NaN concerns here)
static __device__ __forceinline__ unsigned short f2bf(float f) {
    unsigned u = __float_as_uint(f);
    u += 0x7FFFu + ((u >> 16) & 1u);
    return (unsigned short)(u >> 16);
}
static __device__ __forceinline__ float bf2f(unsigned short u) {
    return __uint_as_float(((unsigned)u) << 16);
}

// ---------------------------------------------------------------------------
// Kernel 1: hwb[n,:] = bf16( (h[n,:] @ W) * norm[n] )
// 32-row x 128-col tile per block, 256 threads, 4x4 register blocking.
// ---------------------------------------------------------------------------
__global__ __launch_bounds__(256) void gemm_scale_kernel(
    const float* __restrict__ h, const float* __restrict__ W,
    const float* __restrict__ norm, unsigned short* __restrict__ hwb,
    int n_nodes)
{
    __shared__ float Ws[D * D];     // W[k][col], row-major
    __shared__ float Hs[32 * D];    // h-tile[r][k]

    const int t = threadIdx.x;
    const int row_base = blockIdx.x * 32;

    {
        const float4* W4 = (const float4*)W;
        float4* Ws4 = (float4*)Ws;
        #pragma unroll
        for (int i = 0; i < 16; ++i) Ws4[t + 256 * i] = W4[t + 256 * i];
    }
    {
        const float4* h4 = (const float4*)(h + (long)row_base * D);
        float4* Hs4 = (float4*)Hs;
        #pragma unroll
        for (int i = 0; i < 4; ++i) Hs4[t + 256 * i] = h4[t + 256 * i];
    }
    __syncthreads();

    const int tx = t & 31;
    const int ty = t >> 5;
    const int col0 = tx * 4;
    const int r0 = ty * 4;

    float acc[4][4] = {};

    #pragma unroll 4
    for (int k = 0; k < D; k += 4) {
        float4 a[4], b[4];
        #pragma unroll
        for (int i = 0; i < 4; ++i)
            a[i] = *(const float4*)&Hs[(r0 + i) * D + k];
        #pragma unroll
        for (int j = 0; j < 4; ++j)
            b[j] = *(const float4*)&Ws[(k + j) * D + col0];
        #pragma unroll
        for (int i = 0; i < 4; ++i) {
            acc[i][0] += a[i].x * b[0].x + a[i].y * b[1].x + a[i].z * b[2].x + a[i].w * b[3].x;
            acc[i][1] += a[i].x * b[0].y + a[i].y * b[1].y + a[i].z * b[2].y + a[i].w * b[3].y;
            acc[i][2] += a[i].x * b[0].z + a[i].y * b[1].z + a[i].z * b[2].z + a[i].w * b[3].z;
            acc[i][3] += a[i].x * b[0].w + a[i].y * b[1].w + a[i].z * b[2].w + a[i].w * b[3].w;
        }
    }

    #pragma unroll
    for (int i = 0; i < 4; ++i) {
        const int row = row_base + r0 + i;
        const float nv = norm[row];
        ushort4 o;
        o.x = f2bf(acc[i][0] * nv);
        o.y = f2bf(acc[i][1] * nv);
        o.z = f2bf(acc[i][2] * nv);
        o.w = f2bf(acc[i][3] * nv);
        *(ushort4*)&hwb[(long)row * D + col0] = o;
    }
}

// ---------------------------------------------------------------------------
// srcs_init: fill padded edge array with dummy index n_nodes; zero the dummy
// bf16 row (row n_nodes of hwb).
// ---------------------------------------------------------------------------
__global__ __launch_bounds__(256) void srcs_init_kernel(
    int* __restrict__ srcs, unsigned short* __restrict__ hwb,
    int n_total, int n_nodes)
{
    const int i = blockIdx.x * 256 + threadIdx.x;
    if (i < n_total) srcs[i] = n_nodes;
    if (i < 32) {
        ushort4 z; z.x = z.y = z.z = z.w = 0;
        ((ushort4*)(hwb + (long)n_nodes * D))[i] = z;
    }
}

// ---------------------------------------------------------------------------
// CSR build: histogram -> 2-level exclusive scan (PADDED to x8) -> fill
// hist: 8 edges/thread, fire-and-forget atomics.
// ---------------------------------------------------------------------------
__global__ __launch_bounds__(256) void hist_kernel(
    const int* __restrict__ dst, int* __restrict__ cnt, int n_edges)
{
    const int base = blockIdx.x * 2048 + threadIdx.x;
    #pragma unroll
    for (int k = 0; k < 8; ++k) {
        const int e = base + k * 256;
        if (e < n_edges) atomicAdd(&cnt[dst[e]], 1);
    }
}

// Block scans 1024 counts (padded to multiples of 8); off gets block-local
// exclusive scan of PADDED counts; bsums gets the block total.
__global__ __launch_bounds__(256) void scan_blocks_kernel(
    const int* __restrict__ cnt, int* __restrict__ off,
    int* __restrict__ bsums, int n)
{
    __shared__ int tmp[256];
    const int t = threadIdx.x;
    const int base = blockIdx.x * 1024 + t * 4;

    int v[4];
    int s = 0;
    #pragma unroll
    for (int k = 0; k < 4; ++k) {
        int c = (base + k < n) ? cnt[base + k] : 0;
        v[k] = (c + 7) & ~7;        // pad each segment to multiple of 8
        s += v[k];
    }
    tmp[t] = s;
    __syncthreads();
    for (int ofs = 1; ofs < 256; ofs <<= 1) {
        int x = (t >= ofs) ? tmp[t - ofs] : 0;
        __syncthreads();
        tmp[t] += x;
        __syncthreads();
    }
    int run = tmp[t] - s;
    #pragma unroll
    for (int k = 0; k < 4; ++k) {
        if (base + k < n) off[base + k] = run;
        run += v[k];
    }
    if (t == 255) bsums[blockIdx.x] = tmp[255];
}

__global__ __launch_bounds__(128) void scan_top_kernel(int* __restrict__ bsums, int nb)
{
    __shared__ int tmp[128];
    const int t = threadIdx.x;
    const int orig = (t < nb) ? bsums[t] : 0;
    tmp[t] = orig;
    __syncthreads();
    for (int ofs = 1; ofs < 128; ofs <<= 1) {
        int x = (t >= ofs) ? tmp[t - ofs] : 0;
        __syncthreads();
        tmp[t] += x;
        __syncthreads();
    }
    if (t < nb) bsums[t] = tmp[t] - orig;
}

__global__ __launch_bounds__(256) void scan_add_kernel(
    int* __restrict__ off, int* __restrict__ cur,
    const int* __restrict__ bsums, int n)
{
    const int t = threadIdx.x;
    const int base = blockIdx.x * 1024 + t * 4;
    const int add = bsums[blockIdx.x];
    #pragma unroll
    for (int k = 0; k < 4; ++k) {
        const int i = base + k;
        if (i < n) {
            const int o = off[i] + add;
            off[i] = o;
            cur[i] = o;
        }
    }
}

// fill: 8 edges/thread. Loads first (coalesced), then 8 INDEPENDENT returning
// atomics in flight (MLP=8 on the ~600cyc atomic round trip), then scatters.
__global__ __launch_bounds__(256) void fill_kernel(
    const int* __restrict__ src, const int* __restrict__ dst,
    int* __restrict__ cur, int* __restrict__ srcs, int n_edges)
{
    const int base = blockIdx.x * 2048 + threadIdx.x;
    int d[8], s[8];
    bool ok[8];
    #pragma unroll
    for (int k = 0; k < 8; ++k) {
        const int e = base + k * 256;
        ok[k] = (e < n_edges);
        d[k] = ok[k] ? dst[e] : 0;
        s[k] = ok[k] ? src[e] : 0;
    }
    int pos[8];
    #pragma unroll
    for (int k = 0; k < 8; ++k)
        if (ok[k]) pos[k] = atomicAdd(&cur[d[k]], 1);
    #pragma unroll
    for (int k = 0; k < 8; ++k)
        if (ok[k]) srcs[pos[k]] = s[k];
}

// ---------------------------------------------------------------------------
// Aggregation: 8 nodes per 256-thread block, 32 lanes per node, ushort4
// (4 dims, bf16) per lane. Segments padded to x8 -> inner loop is a fully
// unrolled batch of 8 independent 256B row loads (MLP=8). Edge indices are
// fetched 32-at-a-time and broadcast via __shfl within the 32-lane subgroup.
// Fuses out = agg*norm + bias.
// ---------------------------------------------------------------------------
__global__ __launch_bounds__(256) void agg_kernel(
    const unsigned short* __restrict__ hwb, const int* __restrict__ srcs,
    const int* __restrict__ off, const int* __restrict__ cnt,
    const float* __restrict__ norm, const float* __restrict__ bias,
    float* __restrict__ out, int n_nodes)
{
    const int t = threadIdx.x;
    const int sub = t >> 5;          // node slot within block
    const int lane32 = t & 31;       // dim group (4 dims)
    const int node = blockIdx.x * 8 + sub;
    if (node >= n_nodes) return;

    const int start = off[node];
    const int deg = cnt[node];
    const int nb8 = (deg + 7) >> 3;  // padded batch count

    const ushort4* hw4 = (const ushort4*)hwb;   // row = 32 ushort4

    float4 acc; acc.x = acc.y = acc.z = acc.w = 0.0f;
    int myidx = 0;

    for (int b = 0; b < nb8; ++b) {
        const int q = b & 3;
        if (q == 0) myidx = srcs[start + b * 8 + lane32];  // next 32 edges
        ushort4 v[8];
        #pragma unroll
        for (int jj = 0; jj < 8; ++jj) {
            const int s = __shfl(myidx, q * 8 + jj, 32);
            v[jj] = hw4[(long)s * D4 + lane32];
        }
        #pragma unroll
        for (int jj = 0; jj < 8; ++jj) {
            acc.x += bf2f(v[jj].x);
            acc.y += bf2f(v[jj].y);
            acc.z += bf2f(v[jj].z);
            acc.w += bf2f(v[jj].w);
        }
    }

    const float nv = norm[node];
    const float4 bs = ((const float4*)bias)[lane32];
    float4 o;
    o.x = acc.x * nv + bs.x;
    o.y = acc.y * nv + bs.y;
    o.z = acc.z * nv + bs.z;
    o.w = acc.w * nv + bs.w;
    ((float4*)out)[(long)node * D4 + lane32] = o;
}

// ---------------------------------------------------------------------------
// Fallback path: atomic scatter from bf16 hwb + finalize (ws too small).
// ---------------------------------------------------------------------------
__global__ __launch_bounds__(256) void scatter_kernel(
    const unsigned short* __restrict__ hwb, const int* __restrict__ src,
    const int* __restrict__ dst, float* __restrict__ out, int n_edges)
{
    const int idx = blockIdx.x * 256 + threadIdx.x;
    if (idx >= n_edges * D4) return;
    const int e = idx >> 5;
    const int g = idx & 31;
    const int s = src[e];
    const int d = dst[e];
    const ushort4 v = ((const ushort4*)hwb)[(long)s * D4 + g];
    float* o = out + (long)d * D + g * 4;
    atomicAdd(o + 0, bf2f(v.x));
    atomicAdd(o + 1, bf2f(v.y));
    atomicAdd(o + 2, bf2f(v.z));
    atomicAdd(o + 3, bf2f(v.w));
}

__global__ __launch_bounds__(256) void finalize_kernel(
    float* __restrict__ out, const float* __restrict__ norm,
    const float* __restrict__ bias, int n_nodes)
{
    const int idx = blockIdx.x * 256 + threadIdx.x;
    if (idx >= n_nodes * D4) return;
    const int n = idx >> 5;
    const int g = idx & 31;
    float4 v = ((float4*)out)[idx];
    const float nv = norm[n];
    const float4 b = ((const float4*)bias)[g];
    v.x = v.x * nv + b.x;
    v.y = v.y * nv + b.y;
    v.z = v.z * nv + b.z;
    v.w = v.w * nv + b.w;
    ((float4*)out)[idx] = v;
}

extern "C" void kernel_launch(void* const* d_in, const int* in_sizes, int n_in,
                              void* d_out, int out_size, void* d_ws, size_t ws_size,
                              hipStream_t stream) {
    const float* h    = (const float*)d_in[0];
    const float* norm = (const float*)d_in[1];
    const int*   src  = (const int*)d_in[2];
    const int*   dst  = (const int*)d_in[3];
    const float* W    = (const float*)d_in[4];
    const float* bias = (const float*)d_in[5];
    float* out = (float*)d_out;

    const int n_nodes = in_sizes[1];
    const int n_edges = in_sizes[2];

    // padded srcs worst case: every node pads up to +8, plus read slack
    const int srcs_len = n_edges + 8 * n_nodes + 64;

    // ---- workspace layout (256B aligned) ----
    size_t p = 0;
    auto take = [&](size_t bytes) {
        size_t cur = p;
        p += (bytes + 255) & ~(size_t)255;
        return cur;
    };
    const size_t hwb_off   = take(((size_t)n_nodes + 1) * D * sizeof(unsigned short));
    const size_t cnt_off   = take((size_t)n_nodes * sizeof(int));
    const size_t off_off   = take((size_t)n_nodes * sizeof(int));
    const size_t cur_off   = take((size_t)n_nodes * sizeof(int));
    const size_t bsum_off  = take(1024 * sizeof(int));
    const size_t srcs_off  = take((size_t)srcs_len * sizeof(int));
    const size_t needed = p;

    char* ws = (char*)d_ws;
    unsigned short* hwb = (unsigned short*)(ws + hwb_off);

    const int NB = (n_nodes + 1023) / 1024;   // 98 for N=100K

    // 1) hwb = bf16((h @ W) * norm)
    gemm_scale_kernel<<<(n_nodes + 31) / 32, 256, 0, stream>>>(h, W, norm, hwb, n_nodes);

    if (ws_size >= needed && NB <= 128) {
        int* cnt   = (int*)(ws + cnt_off);
        int* off   = (int*)(ws + off_off);
        int* cur   = (int*)(ws + cur_off);
        int* bsums = (int*)(ws + bsum_off);
        int* srcs  = (int*)(ws + srcs_off);

        srcs_init_kernel<<<(srcs_len + 255) / 256, 256, 0, stream>>>(srcs, hwb, srcs_len, n_nodes);
        hipMemsetAsync(cnt, 0, (size_t)n_nodes * sizeof(int), stream);
        hist_kernel<<<(n_edges + 2047) / 2048, 256, 0, stream>>>(dst, cnt, n_edges);
        scan_blocks_kernel<<<NB, 256, 0, stream>>>(cnt, off, bsums, n_nodes);
        scan_top_kernel<<<1, 128, 0, stream>>>(bsums, NB);
        scan_add_kernel<<<NB, 256, 0, stream>>>(off, cur, bsums, n_nodes);
        fill_kernel<<<(n_edges + 2047) / 2048, 256, 0, stream>>>(src, dst, cur, srcs, n_edges);
        agg_kernel<<<(n_nodes + 7) / 8, 256, 0, stream>>>(hwb, srcs, off, cnt, norm, bias,
                                                          out, n_nodes);
    } else {
        hipMemsetAsync(d_out, 0, (size_t)out_size * sizeof(float), stream);
        const int work = n_edges * D4;
        scatter_kernel<<<(work + 255) / 256, 256, 0, stream>>>(hwb, src, dst, out, n_edges);
        const int work2 = n_nodes * D4;
        finalize_kernel<<<(work2 + 255) / 256, 256, 0, stream>>>(out, norm, bias, n_nodes);
    }
}

// Round 5
// 357.341 us; speedup vs baseline: 7.9914x; 1.0986x over previous
//
#include <hip/hip_runtime.h>
#include <hip/hip_bf16.h>

#define D 128            // D_IN == D_OUT == 128
#define D4 32            // D/4 float4s per row
#define CHUNK 16384      // edges per hist2 / bscatter block
#define MAXB 2048        // max buckets => n_nodes <= 131072 for fast path

typedef __attribute__((ext_vector_type(8))) short bf16x8;
typedef __attribute__((ext_vector_type(4))) float f32x4;

// float -> bf16 round-to-nearest-even
static __device__ __forceinline__ unsigned short f2bf(float f) {
    unsigned u = __float_as_uint(f);
    u += 0x7FFFu + ((u >> 16) & 1u);
    return (unsigned short)(u >> 16);
}
static __device__ __forceinline__ float bf2f(unsigned short u) {
    return __uint_as_float(((unsigned)u) << 16);
}

// ---------------------------------------------------------------------------
// GEMM via bf16 MFMA: hwb[n,:] = bf16( (h[n,:] @ W) * norm[n] )
// 64-row tile/block, 256 thr = 4 waves; wave w handles rows [w*16,w*16+16),
// 8 col-tiles x 4 k-steps of v_mfma_f32_16x16x32_bf16.
// LDS rows padded to 136 ushorts (+16B) to break b128 bank conflicts.
// ---------------------------------------------------------------------------
__global__ __launch_bounds__(256) void gemm_mfma_kernel(
    const float* __restrict__ h, const float* __restrict__ W,
    const float* __restrict__ norm, unsigned short* __restrict__ hwb,
    int n_nodes)
{
    __shared__ unsigned short As[64 * 136];    // [row][k] bf16, padded stride
    __shared__ unsigned short Bs[128 * 136];   // [col][k] bf16 (W^T), padded

    const int t = threadIdx.x;
    const int row0 = blockIdx.x * 64;

    // stage W^T as bf16: read W row-major float4 (coalesced), scatter to Bs
    #pragma unroll
    for (int i = 0; i < 16; ++i) {
        const int idx = t + 256 * i;           // float4 index over 128x32
        const int k = idx >> 5;
        const int c = (idx & 31) * 4;
        const float4 w = ((const float4*)W)[idx];
        Bs[(c + 0) * 136 + k] = f2bf(w.x);
        Bs[(c + 1) * 136 + k] = f2bf(w.y);
        Bs[(c + 2) * 136 + k] = f2bf(w.z);
        Bs[(c + 3) * 136 + k] = f2bf(w.w);
    }
    // stage A tile as bf16 (row-clamped for the tail block)
    #pragma unroll
    for (int i = 0; i < 8; ++i) {
        const int idx = t + 256 * i;           // float4 index over 64x32
        const int r = idx >> 5;
        const int kq = idx & 31;
        long gr = row0 + r; if (gr >= n_nodes) gr = n_nodes - 1;
        const float4 a = ((const float4*)(h + gr * D))[kq];
        ushort4 o;
        o.x = f2bf(a.x); o.y = f2bf(a.y); o.z = f2bf(a.z); o.w = f2bf(a.w);
        *(ushort4*)&As[r * 136 + kq * 4] = o;
    }
    __syncthreads();

    const int wv = t >> 6;
    const int lane = t & 63;
    const int m = lane & 15;        // row-in-tile (A) / col-in-tile (B)
    const int quad = lane >> 4;     // k-block selector

    f32x4 acc[8];
    #pragma unroll
    for (int nt = 0; nt < 8; ++nt) { f32x4 z = {0.f, 0.f, 0.f, 0.f}; acc[nt] = z; }

    #pragma unroll
    for (int kt = 0; kt < 4; ++kt) {
        const bf16x8 af = *(const bf16x8*)&As[(wv * 16 + m) * 136 + kt * 32 + quad * 8];
        #pragma unroll
        for (int nt = 0; nt < 8; ++nt) {
            const bf16x8 bfr = *(const bf16x8*)&Bs[(nt * 16 + m) * 136 + kt * 32 + quad * 8];
            acc[nt] = __builtin_amdgcn_mfma_f32_16x16x32_bf16(af, bfr, acc[nt], 0, 0, 0);
        }
    }

    // epilogue: C/D layout col=lane&15, row=quad*4+i
    float nv[4];
    #pragma unroll
    for (int i = 0; i < 4; ++i) {
        const int gr = row0 + wv * 16 + quad * 4 + i;
        nv[i] = (gr < n_nodes) ? norm[gr] : 0.f;
    }
    #pragma unroll
    for (int nt = 0; nt < 8; ++nt) {
        #pragma unroll
        for (int i = 0; i < 4; ++i) {
            const int gr = row0 + wv * 16 + quad * 4 + i;
            if (gr < n_nodes)
                hwb[(size_t)gr * D + nt * 16 + m] = f2bf(acc[nt][i] * nv[i]);
        }
    }
}

// ---------------------------------------------------------------------------
// hist2: per-node count (global fire-forget atomics) + per-bucket count
// (LDS-staged, one flush atomic per (block,bucket)). Block 0 zeroes the
// dummy hwb row n_nodes.
// ---------------------------------------------------------------------------
__global__ __launch_bounds__(256) void hist2_kernel(
    const int* __restrict__ dst, int* __restrict__ cnt,
    int* __restrict__ bcnt, unsigned short* __restrict__ hwb,
    int n_edges, int n_nodes)
{
    __shared__ int lbh[MAXB];
    const int t = threadIdx.x;
    for (int i = t; i < MAXB; i += 256) lbh[i] = 0;
    if (blockIdx.x == 0 && t < 32) {
        ushort4 z; z.x = z.y = z.z = z.w = 0;
        ((ushort4*)(hwb + (size_t)n_nodes * D))[t] = z;
    }
    __syncthreads();
    const int e0 = blockIdx.x * CHUNK;
    const int e1 = min(e0 + CHUNK, n_edges);
    for (int e = e0 + t; e < e1; e += 256) {
        const int d = dst[e];
        atomicAdd(&cnt[d], 1);
        atomicAdd(&lbh[d >> 6], 1);
    }
    __syncthreads();
    for (int i = t; i < MAXB; i += 256) {
        const int c = lbh[i];
        if (c) atomicAdd(&bcnt[i], c);
    }
}

// ---------------------------------------------------------------------------
// Per-node padded scan (unchanged from R4): off = exclusive scan of
// cnt padded to multiples of 8.
// ---------------------------------------------------------------------------
__global__ __launch_bounds__(256) void scan_blocks_kernel(
    const int* __restrict__ cnt, int* __restrict__ off,
    int* __restrict__ bsums, int n)
{
    __shared__ int tmp[256];
    const int t = threadIdx.x;
    const int base = blockIdx.x * 1024 + t * 4;

    int v[4];
    int s = 0;
    #pragma unroll
    for (int k = 0; k < 4; ++k) {
        int c = (base + k < n) ? cnt[base + k] : 0;
        v[k] = (c + 7) & ~7;
        s += v[k];
    }
    tmp[t] = s;
    __syncthreads();
    for (int ofs = 1; ofs < 256; ofs <<= 1) {
        int x = (t >= ofs) ? tmp[t - ofs] : 0;
        __syncthreads();
        tmp[t] += x;
        __syncthreads();
    }
    int run = tmp[t] - s;
    #pragma unroll
    for (int k = 0; k < 4; ++k) {
        if (base + k < n) off[base + k] = run;
        run += v[k];
    }
    if (t == 255) bsums[blockIdx.x] = tmp[255];
}

__global__ __launch_bounds__(128) void scan_top_kernel(int* __restrict__ bsums, int nb)
{
    __shared__ int tmp[128];
    const int t = threadIdx.x;
    const int orig = (t < nb) ? bsums[t] : 0;
    tmp[t] = orig;
    __syncthreads();
    for (int ofs = 1; ofs < 128; ofs <<= 1) {
        int x = (t >= ofs) ? tmp[t - ofs] : 0;
        __syncthreads();
        tmp[t] += x;
        __syncthreads();
    }
    if (t < nb) bsums[t] = tmp[t] - orig;
}

__global__ __launch_bounds__(256) void scan_add_kernel(
    int* __restrict__ off, const int* __restrict__ bsums, int n)
{
    const int t = threadIdx.x;
    const int base = blockIdx.x * 1024 + t * 4;
    const int add = bsums[blockIdx.x];
    #pragma unroll
    for (int k = 0; k < 4; ++k) {
        const int i = base + k;
        if (i < n) off[i] += add;
    }
}

// ---------------------------------------------------------------------------
// bscan: single block, exclusive scan of 2048 bucket counts -> boff, bcur.
// ---------------------------------------------------------------------------
__global__ __launch_bounds__(256) void bscan_kernel(
    const int* __restrict__ bcnt, int* __restrict__ boff, int* __restrict__ bcur)
{
    __shared__ int tmp[256];
    const int t = threadIdx.x;
    int v[8];
    int s = 0;
    #pragma unroll
    for (int k = 0; k < 8; ++k) { v[k] = bcnt[t * 8 + k]; s += v[k]; }
    tmp[t] = s;
    __syncthreads();
    for (int ofs = 1; ofs < 256; ofs <<= 1) {
        int x = (t >= ofs) ? tmp[t - ofs] : 0;
        __syncthreads();
        tmp[t] += x;
        __syncthreads();
    }
    int run = tmp[t] - s;
    #pragma unroll
    for (int k = 0; k < 8; ++k) {
        boff[t * 8 + k] = run;
        bcur[t * 8 + k] = run;
        run += v[k];
    }
    if (t == 255) boff[MAXB] = run;
}

// ---------------------------------------------------------------------------
// bscatter: LDS-staged bucketing. Per 16K-edge block: LDS histogram,
// one cursor-reservation atomic per present bucket, LDS-ranked scatter of
// packed records (src | (dst&63)<<17) into bucket-major ebuf.
// ---------------------------------------------------------------------------
__global__ __launch_bounds__(256) void bscatter_kernel(
    const int* __restrict__ src, const int* __restrict__ dst,
    int* __restrict__ bcur, unsigned int* __restrict__ ebuf, int n_edges)
{
    __shared__ int lbh[MAXB];
    __shared__ int lofs[MAXB];
    const int t = threadIdx.x;
    for (int i = t; i < MAXB; i += 256) lbh[i] = 0;
    __syncthreads();
    const int e0 = blockIdx.x * CHUNK;
    const int e1 = min(e0 + CHUNK, n_edges);
    for (int e = e0 + t; e < e1; e += 256)
        atomicAdd(&lbh[dst[e] >> 6], 1);
    __syncthreads();
    for (int i = t; i < MAXB; i += 256) {
        const int c = lbh[i];
        lofs[i] = c ? atomicAdd(&bcur[i], c) : 0;
    }
    __syncthreads();
    for (int i = t; i < MAXB; i += 256) lbh[i] = 0;
    __syncthreads();
    for (int e = e0 + t; e < e1; e += 256) {
        const int d = dst[e];
        const int bk = d >> 6;
        const int r = atomicAdd(&lbh[bk], 1);
        ebuf[lofs[bk] + r] = (unsigned)src[e] | ((unsigned)(d & 63) << 17);
    }
}

// ---------------------------------------------------------------------------
// fill_local: one block per bucket (64 nodes). LDS cursors (no global
// atomics); scatter srcs within the bucket's small contiguous window
// (L2 write-combined), then write the <=7 dummy pad slots per node.
// ---------------------------------------------------------------------------
__global__ __launch_bounds__(256) void fill_local_kernel(
    const unsigned int* __restrict__ ebuf, const int* __restrict__ boff,
    const int* __restrict__ off, const int* __restrict__ cnt,
    int* __restrict__ srcs, int n_nodes)
{
    __shared__ int lcur[64];
    const int t = threadIdx.x;
    const int b = blockIdx.x;
    const int gn0 = b * 64;
    if (t < 64) {
        const int gn = gn0 + t;
        lcur[t] = (gn < n_nodes) ? off[gn] : 0;
    }
    __syncthreads();
    const int e0 = boff[b], e1 = boff[b + 1];
    for (int e = e0 + t; e < e1; e += 256) {
        const unsigned rec = ebuf[e];
        const int loc = (rec >> 17) & 63;
        const int pos = atomicAdd(&lcur[loc], 1);
        srcs[pos] = (int)(rec & 0x1FFFFu);
    }
    // pad fill: disjoint slots, no barrier needed
    for (int w = t; w < 512; w += 256) {
        const int ln = w >> 3, k = w & 7;
        const int gn = gn0 + ln;
        if (gn < n_nodes) {
            const int c = cnt[gn];
            const int pad = (8 - (c & 7)) & 7;
            if (k < pad) srcs[off[gn] + c + k] = n_nodes;
        }
    }
}

// ---------------------------------------------------------------------------
// Aggregation (unchanged from R4): 8 nodes/block, 32 lanes/node, ushort4
// bf16 gathers, MLP=8 via x8 segment padding. Fuses out = agg*norm + bias.
// ---------------------------------------------------------------------------
__global__ __launch_bounds__(256) void agg_kernel(
    const unsigned short* __restrict__ hwb, const int* __restrict__ srcs,
    const int* __restrict__ off, const int* __restrict__ cnt,
    const float* __restrict__ norm, const float* __restrict__ bias,
    float* __restrict__ out, int n_nodes)
{
    const int t = threadIdx.x;
    const int sub = t >> 5;
    const int lane32 = t & 31;
    const int node = blockIdx.x * 8 + sub;
    if (node >= n_nodes) return;

    const int start = off[node];
    const int deg = cnt[node];
    const int nb8 = (deg + 7) >> 3;

    const ushort4* hw4 = (const ushort4*)hwb;

    float4 acc; acc.x = acc.y = acc.z = acc.w = 0.0f;
    int myidx = 0;

    for (int b = 0; b < nb8; ++b) {
        const int q = b & 3;
        if (q == 0) myidx = srcs[start + b * 8 + lane32];
        ushort4 v[8];
        #pragma unroll
        for (int jj = 0; jj < 8; ++jj) {
            const int s = __shfl(myidx, q * 8 + jj, 32);
            v[jj] = hw4[(long)s * D4 + lane32];
        }
        #pragma unroll
        for (int jj = 0; jj < 8; ++jj) {
            acc.x += bf2f(v[jj].x);
            acc.y += bf2f(v[jj].y);
            acc.z += bf2f(v[jj].z);
            acc.w += bf2f(v[jj].w);
        }
    }

    const float nv = norm[node];
    const float4 bs = ((const float4*)bias)[lane32];
    float4 o;
    o.x = acc.x * nv + bs.x;
    o.y = acc.y * nv + bs.y;
    o.z = acc.z * nv + bs.z;
    o.w = acc.w * nv + bs.w;
    ((float4*)out)[(long)node * D4 + lane32] = o;
}

// ---------------------------------------------------------------------------
// Fallback path: atomic scatter from bf16 hwb + finalize (ws too small).
// ---------------------------------------------------------------------------
__global__ __launch_bounds__(256) void scatter_kernel(
    const unsigned short* __restrict__ hwb, const int* __restrict__ src,
    const int* __restrict__ dst, float* __restrict__ out, int n_edges)
{
    const int idx = blockIdx.x * 256 + threadIdx.x;
    if (idx >= n_edges * D4) return;
    const int e = idx >> 5;
    const int g = idx & 31;
    const int s = src[e];
    const int d = dst[e];
    const ushort4 v = ((const ushort4*)hwb)[(long)s * D4 + g];
    float* o = out + (long)d * D + g * 4;
    atomicAdd(o + 0, bf2f(v.x));
    atomicAdd(o + 1, bf2f(v.y));
    atomicAdd(o + 2, bf2f(v.z));
    atomicAdd(o + 3, bf2f(v.w));
}

__global__ __launch_bounds__(256) void finalize_kernel(
    float* __restrict__ out, const float* __restrict__ norm,
    const float* __restrict__ bias, int n_nodes)
{
    const int idx = blockIdx.x * 256 + threadIdx.x;
    if (idx >= n_nodes * D4) return;
    const int n = idx >> 5;
    const int g = idx & 31;
    float4 v = ((float4*)out)[idx];
    const float nv = norm[n];
    const float4 b = ((const float4*)bias)[g];
    v.x = v.x * nv + b.x;
    v.y = v.y * nv + b.y;
    v.z = v.z * nv + b.z;
    v.w = v.w * nv + b.w;
    ((float4*)out)[idx] = v;
}

extern "C" void kernel_launch(void* const* d_in, const int* in_sizes, int n_in,
                              void* d_out, int out_size, void* d_ws, size_t ws_size,
                              hipStream_t stream) {
    const float* h    = (const float*)d_in[0];
    const float* norm = (const float*)d_in[1];
    const int*   src  = (const int*)d_in[2];
    const int*   dst  = (const int*)d_in[3];
    const float* W    = (const float*)d_in[4];
    const float* bias = (const float*)d_in[5];
    float* out = (float*)d_out;

    const int n_nodes = in_sizes[1];
    const int n_edges = in_sizes[2];

    const int srcs_len = n_edges + 8 * n_nodes + 64;
    const int NB    = (n_nodes + 1023) / 1024;       // per-node scan blocks
    const int NBUCK = (n_nodes + 63) >> 6;           // buckets (64 nodes each)
    const int EB    = (n_edges + CHUNK - 1) / CHUNK; // edge chunks

    // ---- workspace layout (256B aligned) ----
    size_t p = 0;
    auto take = [&](size_t bytes) {
        size_t cur = p;
        p += (bytes + 255) & ~(size_t)255;
        return cur;
    };
    const size_t hwb_off  = take(((size_t)n_nodes + 1) * D * sizeof(unsigned short));
    const size_t cnt_off  = take((size_t)n_nodes * sizeof(int));
    const size_t off_off  = take((size_t)n_nodes * sizeof(int));
    const size_t bsum_off = take(1024 * sizeof(int));
    const size_t srcs_off = take((size_t)srcs_len * sizeof(int));
    const size_t ebuf_off = take((size_t)n_edges * sizeof(unsigned int));
    const size_t bcnt_off = take(MAXB * sizeof(int));
    const size_t boff_off = take((MAXB + 1) * sizeof(int));
    const size_t bcur_off = take(MAXB * sizeof(int));
    const size_t needed = p;

    char* ws = (char*)d_ws;
    unsigned short* hwb = (unsigned short*)(ws + hwb_off);

    // 1) hwb = bf16((h @ W) * norm) via MFMA
    gemm_mfma_kernel<<<(n_nodes + 63) / 64, 256, 0, stream>>>(h, W, norm, hwb, n_nodes);

    if (ws_size >= needed && NB <= 128 && NBUCK <= MAXB && n_nodes <= 131072) {
        int* cnt   = (int*)(ws + cnt_off);
        int* off   = (int*)(ws + off_off);
        int* bsums = (int*)(ws + bsum_off);
        int* srcs  = (int*)(ws + srcs_off);
        unsigned int* ebuf = (unsigned int*)(ws + ebuf_off);
        int* bcnt  = (int*)(ws + bcnt_off);
        int* boff  = (int*)(ws + boff_off);
        int* bcur  = (int*)(ws + bcur_off);

        hipMemsetAsync(cnt, 0, (size_t)n_nodes * sizeof(int), stream);
        hipMemsetAsync(bcnt, 0, MAXB * sizeof(int), stream);

        hist2_kernel<<<EB, 256, 0, stream>>>(dst, cnt, bcnt, hwb, n_edges, n_nodes);
        scan_blocks_kernel<<<NB, 256, 0, stream>>>(cnt, off, bsums, n_nodes);
        scan_top_kernel<<<1, 128, 0, stream>>>(bsums, NB);
        scan_add_kernel<<<NB, 256, 0, stream>>>(off, bsums, n_nodes);
        bscan_kernel<<<1, 256, 0, stream>>>(bcnt, boff, bcur);
        bscatter_kernel<<<EB, 256, 0, stream>>>(src, dst, bcur, ebuf, n_edges);
        fill_local_kernel<<<NBUCK, 256, 0, stream>>>(ebuf, boff, off, cnt, srcs, n_nodes);
        agg_kernel<<<(n_nodes + 7) / 8, 256, 0, stream>>>(hwb, srcs, off, cnt, norm, bias,
                                                          out, n_nodes);
    } else {
        hipMemsetAsync(d_out, 0, (size_t)out_size * sizeof(float), stream);
        const int work = n_edges * D4;
        scatter_kernel<<<(work + 255) / 256, 256, 0, stream>>>(hwb, src, dst, out, n_edges);
        const int work2 = n_nodes * D4;
        finalize_kernel<<<(work2 + 255) / 256, 256, 0, stream>>>(out, norm, bias, n_nodes);
    }
}

// Round 6
// 331.096 us; speedup vs baseline: 8.6248x; 1.0793x over previous
//
#include <hip/hip_runtime.h>
#include <hip/hip_bf16.h>

#define D 128            // D_IN == D_OUT == 128
#define D4 32            // D/4 float4s per row
#define CHUNK 3072       // edges per hist2 / bscatter block (1024 threads)
#define MAXB 2048        // max buckets => n_nodes <= 131072 for fast path

typedef __attribute__((ext_vector_type(8))) short bf16x8;
typedef __attribute__((ext_vector_type(4))) float f32x4;

// float -> bf16 round-to-nearest-even
static __device__ __forceinline__ unsigned short f2bf(float f) {
    unsigned u = __float_as_uint(f);
    u += 0x7FFFu + ((u >> 16) & 1u);
    return (unsigned short)(u >> 16);
}
static __device__ __forceinline__ float bf2f(unsigned short u) {
    return __uint_as_float(((unsigned)u) << 16);
}

// ---------------------------------------------------------------------------
// GEMM via bf16 MFMA: hwb[n,:] = bf16( (h[n,:] @ W) * norm[n] )
// 64-row tile/block, 256 thr = 4 waves; wave w handles rows [w*16,w*16+16),
// 8 col-tiles x 4 k-steps of v_mfma_f32_16x16x32_bf16.
// LDS rows padded to 136 ushorts (+16B) to break b128 bank conflicts.
// ---------------------------------------------------------------------------
__global__ __launch_bounds__(256) void gemm_mfma_kernel(
    const float* __restrict__ h, const float* __restrict__ W,
    const float* __restrict__ norm, unsigned short* __restrict__ hwb,
    int n_nodes)
{
    __shared__ unsigned short As[64 * 136];    // [row][k] bf16, padded stride
    __shared__ unsigned short Bs[128 * 136];   // [col][k] bf16 (W^T), padded

    const int t = threadIdx.x;
    const int row0 = blockIdx.x * 64;

    #pragma unroll
    for (int i = 0; i < 16; ++i) {
        const int idx = t + 256 * i;           // float4 index over 128x32
        const int k = idx >> 5;
        const int c = (idx & 31) * 4;
        const float4 w = ((const float4*)W)[idx];
        Bs[(c + 0) * 136 + k] = f2bf(w.x);
        Bs[(c + 1) * 136 + k] = f2bf(w.y);
        Bs[(c + 2) * 136 + k] = f2bf(w.z);
        Bs[(c + 3) * 136 + k] = f2bf(w.w);
    }
    #pragma unroll
    for (int i = 0; i < 8; ++i) {
        const int idx = t + 256 * i;           // float4 index over 64x32
        const int r = idx >> 5;
        const int kq = idx & 31;
        long gr = row0 + r; if (gr >= n_nodes) gr = n_nodes - 1;
        const float4 a = ((const float4*)(h + gr * D))[kq];
        ushort4 o;
        o.x = f2bf(a.x); o.y = f2bf(a.y); o.z = f2bf(a.z); o.w = f2bf(a.w);
        *(ushort4*)&As[r * 136 + kq * 4] = o;
    }
    __syncthreads();

    const int wv = t >> 6;
    const int lane = t & 63;
    const int m = lane & 15;
    const int quad = lane >> 4;

    f32x4 acc[8];
    #pragma unroll
    for (int nt = 0; nt < 8; ++nt) { f32x4 z = {0.f, 0.f, 0.f, 0.f}; acc[nt] = z; }

    #pragma unroll
    for (int kt = 0; kt < 4; ++kt) {
        const bf16x8 af = *(const bf16x8*)&As[(wv * 16 + m) * 136 + kt * 32 + quad * 8];
        #pragma unroll
        for (int nt = 0; nt < 8; ++nt) {
            const bf16x8 bfr = *(const bf16x8*)&Bs[(nt * 16 + m) * 136 + kt * 32 + quad * 8];
            acc[nt] = __builtin_amdgcn_mfma_f32_16x16x32_bf16(af, bfr, acc[nt], 0, 0, 0);
        }
    }

    float nv[4];
    #pragma unroll
    for (int i = 0; i < 4; ++i) {
        const int gr = row0 + wv * 16 + quad * 4 + i;
        nv[i] = (gr < n_nodes) ? norm[gr] : 0.f;
    }
    #pragma unroll
    for (int nt = 0; nt < 8; ++nt) {
        #pragma unroll
        for (int i = 0; i < 4; ++i) {
            const int gr = row0 + wv * 16 + quad * 4 + i;
            if (gr < n_nodes)
                hwb[(size_t)gr * D + nt * 16 + m] = f2bf(acc[nt][i] * nv[i]);
        }
    }
}

// ---------------------------------------------------------------------------
// hist2 (1024 thr, CHUNK edges): per-node cnt (fire-forget atomics) +
// LDS bucket hist; persists its hist row H[g][*] (coalesced) and
// atomic-accumulates bcnt. Block 0 zeroes the dummy hwb row.
// ---------------------------------------------------------------------------
__global__ __launch_bounds__(1024) void hist2_kernel(
    const int* __restrict__ dst, int* __restrict__ cnt,
    int* __restrict__ H, int* __restrict__ bcnt,
    unsigned short* __restrict__ hwb, int n_edges, int n_nodes)
{
    __shared__ int lbh[MAXB];
    const int t = threadIdx.x;
    const int g = blockIdx.x;
    for (int i = t; i < MAXB; i += 1024) lbh[i] = 0;
    if (g == 0 && t < 32) {
        ushort4 z; z.x = z.y = z.z = z.w = 0;
        ((ushort4*)(hwb + (size_t)n_nodes * D))[t] = z;
    }
    __syncthreads();
    const int e0 = g * CHUNK;
    const int e1 = min(e0 + CHUNK, n_edges);
    for (int e = e0 + t; e < e1; e += 1024) {
        const int d = dst[e];
        atomicAdd(&cnt[d], 1);
        atomicAdd(&lbh[d >> 6], 1);
    }
    __syncthreads();
    for (int i = t; i < MAXB; i += 1024) {
        const int c = lbh[i];
        H[(size_t)g * MAXB + i] = c;
        if (c) atomicAdd(&bcnt[i], c);
    }
}

// ---------------------------------------------------------------------------
// Per-node padded scan: off = exclusive scan of cnt padded to x8.
// ---------------------------------------------------------------------------
__global__ __launch_bounds__(256) void scan_blocks_kernel(
    const int* __restrict__ cnt, int* __restrict__ off,
    int* __restrict__ bsums, int n)
{
    __shared__ int tmp[256];
    const int t = threadIdx.x;
    const int base = blockIdx.x * 1024 + t * 4;

    int v[4];
    int s = 0;
    #pragma unroll
    for (int k = 0; k < 4; ++k) {
        int c = (base + k < n) ? cnt[base + k] : 0;
        v[k] = (c + 7) & ~7;
        s += v[k];
    }
    tmp[t] = s;
    __syncthreads();
    for (int ofs = 1; ofs < 256; ofs <<= 1) {
        int x = (t >= ofs) ? tmp[t - ofs] : 0;
        __syncthreads();
        tmp[t] += x;
        __syncthreads();
    }
    int run = tmp[t] - s;
    #pragma unroll
    for (int k = 0; k < 4; ++k) {
        if (base + k < n) off[base + k] = run;
        run += v[k];
    }
    if (t == 255) bsums[blockIdx.x] = tmp[255];
}

// ---------------------------------------------------------------------------
// Fused top-level scans: block 0 scans bsums (nb <= 256); block 1 scans the
// MAXB bucket counts -> boff, bcur.
// ---------------------------------------------------------------------------
__global__ __launch_bounds__(256) void top_scans_kernel(
    int* __restrict__ bsums, int nb,
    const int* __restrict__ bcnt, int* __restrict__ boff, int* __restrict__ bcur)
{
    __shared__ int tmp[256];
    const int t = threadIdx.x;
    if (blockIdx.x == 0) {
        const int orig = (t < nb) ? bsums[t] : 0;
        tmp[t] = orig;
        __syncthreads();
        for (int ofs = 1; ofs < 256; ofs <<= 1) {
            int x = (t >= ofs) ? tmp[t - ofs] : 0;
            __syncthreads();
            tmp[t] += x;
            __syncthreads();
        }
        if (t < nb) bsums[t] = tmp[t] - orig;
    } else {
        int v[8];
        int s = 0;
        #pragma unroll
        for (int k = 0; k < 8; ++k) { v[k] = bcnt[t * 8 + k]; s += v[k]; }
        tmp[t] = s;
        __syncthreads();
        for (int ofs = 1; ofs < 256; ofs <<= 1) {
            int x = (t >= ofs) ? tmp[t - ofs] : 0;
            __syncthreads();
            tmp[t] += x;
            __syncthreads();
        }
        int run = tmp[t] - s;
        #pragma unroll
        for (int k = 0; k < 8; ++k) {
            boff[t * 8 + k] = run;
            bcur[t * 8 + k] = run;
            run += v[k];
        }
        if (t == 255) boff[MAXB] = run;
    }
}

__global__ __launch_bounds__(256) void scan_add_kernel(
    int* __restrict__ off, const int* __restrict__ bsums, int n)
{
    const int t = threadIdx.x;
    const int base = blockIdx.x * 1024 + t * 4;
    const int add = bsums[blockIdx.x];
    #pragma unroll
    for (int k = 0; k < 4; ++k) {
        const int i = base + k;
        if (i < n) off[i] += add;
    }
}

// ---------------------------------------------------------------------------
// bscatter (1024 thr): load own hist row H[g][*], reserve bucket windows via
// returning atomics, then LDS-ranked scatter of packed records
// (src | (dst&63)<<17) into bucket-major ebuf. 2 passes over edges -> 1.
// ---------------------------------------------------------------------------
__global__ __launch_bounds__(1024) void bscatter_kernel(
    const int* __restrict__ src, const int* __restrict__ dst,
    const int* __restrict__ H, int* __restrict__ bcur,
    unsigned int* __restrict__ ebuf, int n_edges)
{
    __shared__ int lbh[MAXB];
    __shared__ int lofs[MAXB];
    const int t = threadIdx.x;
    const int g = blockIdx.x;
    for (int i = t; i < MAXB; i += 1024) {
        lbh[i] = 0;
        const int c = H[(size_t)g * MAXB + i];
        lofs[i] = c ? atomicAdd(&bcur[i], c) : 0;
    }
    __syncthreads();
    const int e0 = g * CHUNK;
    const int e1 = min(e0 + CHUNK, n_edges);
    for (int e = e0 + t; e < e1; e += 1024) {
        const int d = dst[e];
        const int bk = d >> 6;
        const int r = atomicAdd(&lbh[bk], 1);
        ebuf[lofs[bk] + r] = (unsigned)src[e] | ((unsigned)(d & 63) << 17);
    }
}

// ---------------------------------------------------------------------------
// fill_local: one block per bucket (64 nodes). LDS cursors (no global
// atomics); scatter srcs within the bucket's contiguous window, then write
// the <=7 dummy pad slots per node.
// ---------------------------------------------------------------------------
__global__ __launch_bounds__(256) void fill_local_kernel(
    const unsigned int* __restrict__ ebuf, const int* __restrict__ boff,
    const int* __restrict__ off, const int* __restrict__ cnt,
    int* __restrict__ srcs, int n_nodes)
{
    __shared__ int lcur[64];
    const int t = threadIdx.x;
    const int b = blockIdx.x;
    const int gn0 = b * 64;
    if (t < 64) {
        const int gn = gn0 + t;
        lcur[t] = (gn < n_nodes) ? off[gn] : 0;
    }
    __syncthreads();
    const int e0 = boff[b], e1 = boff[b + 1];
    for (int e = e0 + t; e < e1; e += 256) {
        const unsigned rec = ebuf[e];
        const int loc = (rec >> 17) & 63;
        const int pos = atomicAdd(&lcur[loc], 1);
        srcs[pos] = (int)(rec & 0x1FFFFu);
    }
    for (int w = t; w < 512; w += 256) {
        const int ln = w >> 3, k = w & 7;
        const int gn = gn0 + ln;
        if (gn < n_nodes) {
            const int c = cnt[gn];
            const int pad = (8 - (c & 7)) & 7;
            if (k < pad) srcs[off[gn] + c + k] = n_nodes;
        }
    }
}

// ---------------------------------------------------------------------------
// Aggregation: 8 nodes/block, 32 lanes/node, ushort4 bf16 gathers, MLP=8 via
// x8 segment padding. Fuses out = agg*norm + bias.
// ---------------------------------------------------------------------------
__global__ __launch_bounds__(256) void agg_kernel(
    const unsigned short* __restrict__ hwb, const int* __restrict__ srcs,
    const int* __restrict__ off, const int* __restrict__ cnt,
    const float* __restrict__ norm, const float* __restrict__ bias,
    float* __restrict__ out, int n_nodes)
{
    const int t = threadIdx.x;
    const int sub = t >> 5;
    const int lane32 = t & 31;
    const int node = blockIdx.x * 8 + sub;
    if (node >= n_nodes) return;

    const int start = off[node];
    const int deg = cnt[node];
    const int nb8 = (deg + 7) >> 3;

    const ushort4* hw4 = (const ushort4*)hwb;

    float4 acc; acc.x = acc.y = acc.z = acc.w = 0.0f;
    int myidx = 0;

    for (int b = 0; b < nb8; ++b) {
        const int q = b & 3;
        if (q == 0) myidx = srcs[start + b * 8 + lane32];
        ushort4 v[8];
        #pragma unroll
        for (int jj = 0; jj < 8; ++jj) {
            const int s = __shfl(myidx, q * 8 + jj, 32);
            v[jj] = hw4[(long)s * D4 + lane32];
        }
        #pragma unroll
        for (int jj = 0; jj < 8; ++jj) {
            acc.x += bf2f(v[jj].x);
            acc.y += bf2f(v[jj].y);
            acc.z += bf2f(v[jj].z);
            acc.w += bf2f(v[jj].w);
        }
    }

    const float nv = norm[node];
    const float4 bs = ((const float4*)bias)[lane32];
    float4 o;
    o.x = acc.x * nv + bs.x;
    o.y = acc.y * nv + bs.y;
    o.z = acc.z * nv + bs.z;
    o.w = acc.w * nv + bs.w;
    ((float4*)out)[(long)node * D4 + lane32] = o;
}

// ---------------------------------------------------------------------------
// Fallback path: atomic scatter from bf16 hwb + finalize (ws too small).
// ---------------------------------------------------------------------------
__global__ __launch_bounds__(256) void scatter_kernel(
    const unsigned short* __restrict__ hwb, const int* __restrict__ src,
    const int* __restrict__ dst, float* __restrict__ out, int n_edges)
{
    const int idx = blockIdx.x * 256 + threadIdx.x;
    if (idx >= n_edges * D4) return;
    const int e = idx >> 5;
    const int g = idx & 31;
    const int s = src[e];
    const int d = dst[e];
    const ushort4 v = ((const ushort4*)hwb)[(long)s * D4 + g];
    float* o = out + (long)d * D + g * 4;
    atomicAdd(o + 0, bf2f(v.x));
    atomicAdd(o + 1, bf2f(v.y));
    atomicAdd(o + 2, bf2f(v.z));
    atomicAdd(o + 3, bf2f(v.w));
}

__global__ __launch_bounds__(256) void finalize_kernel(
    float* __restrict__ out, const float* __restrict__ norm,
    const float* __restrict__ bias, int n_nodes)
{
    const int idx = blockIdx.x * 256 + threadIdx.x;
    if (idx >= n_nodes * D4) return;
    const int n = idx >> 5;
    const int g = idx & 31;
    float4 v = ((float4*)out)[idx];
    const float nv = norm[n];
    const float4 b = ((const float4*)bias)[g];
    v.x = v.x * nv + b.x;
    v.y = v.y * nv + b.y;
    v.z = v.z * nv + b.z;
    v.w = v.w * nv + b.w;
    ((float4*)out)[idx] = v;
}

extern "C" void kernel_launch(void* const* d_in, const int* in_sizes, int n_in,
                              void* d_out, int out_size, void* d_ws, size_t ws_size,
                              hipStream_t stream) {
    const float* h    = (const float*)d_in[0];
    const float* norm = (const float*)d_in[1];
    const int*   src  = (const int*)d_in[2];
    const int*   dst  = (const int*)d_in[3];
    const float* W    = (const float*)d_in[4];
    const float* bias = (const float*)d_in[5];
    float* out = (float*)d_out;

    const int n_nodes = in_sizes[1];
    const int n_edges = in_sizes[2];

    const int srcs_len = n_edges + 8 * n_nodes + 64;
    const int NB    = (n_nodes + 1023) / 1024;       // per-node scan blocks
    const int NBUCK = (n_nodes + 63) >> 6;           // buckets (64 nodes each)
    const int EB    = (n_edges + CHUNK - 1) / CHUNK; // edge chunks (521)

    // ---- workspace layout (256B aligned) ----
    size_t p = 0;
    auto take = [&](size_t bytes) {
        size_t cur = p;
        p += (bytes + 255) & ~(size_t)255;
        return cur;
    };
    const size_t hwb_off  = take(((size_t)n_nodes + 1) * D * sizeof(unsigned short));
    const size_t cnt_off  = take((size_t)n_nodes * sizeof(int));
    const size_t off_off  = take((size_t)n_nodes * sizeof(int));
    const size_t bsum_off = take(1024 * sizeof(int));
    const size_t srcs_off = take((size_t)srcs_len * sizeof(int));
    const size_t ebuf_off = take((size_t)n_edges * sizeof(unsigned int));
    const size_t bcnt_off = take(MAXB * sizeof(int));
    const size_t boff_off = take((MAXB + 1) * sizeof(int));
    const size_t bcur_off = take(MAXB * sizeof(int));
    const size_t H_off    = take((size_t)EB * MAXB * sizeof(int));
    const size_t needed = p;

    char* ws = (char*)d_ws;
    unsigned short* hwb = (unsigned short*)(ws + hwb_off);

    // 1) hwb = bf16((h @ W) * norm) via MFMA
    gemm_mfma_kernel<<<(n_nodes + 63) / 64, 256, 0, stream>>>(h, W, norm, hwb, n_nodes);

    if (ws_size >= needed && NB <= 256 && NBUCK <= MAXB && n_nodes <= 131072) {
        int* cnt   = (int*)(ws + cnt_off);
        int* off   = (int*)(ws + off_off);
        int* bsums = (int*)(ws + bsum_off);
        int* srcs  = (int*)(ws + srcs_off);
        unsigned int* ebuf = (unsigned int*)(ws + ebuf_off);
        int* bcnt  = (int*)(ws + bcnt_off);
        int* boff  = (int*)(ws + boff_off);
        int* bcur  = (int*)(ws + bcur_off);
        int* H     = (int*)(ws + H_off);

        hipMemsetAsync(cnt, 0, (size_t)n_nodes * sizeof(int), stream);
        hipMemsetAsync(bcnt, 0, MAXB * sizeof(int), stream);

        hist2_kernel<<<EB, 1024, 0, stream>>>(dst, cnt, H, bcnt, hwb, n_edges, n_nodes);
        scan_blocks_kernel<<<NB, 256, 0, stream>>>(cnt, off, bsums, n_nodes);
        top_scans_kernel<<<2, 256, 0, stream>>>(bsums, NB, bcnt, boff, bcur);
        scan_add_kernel<<<NB, 256, 0, stream>>>(off, bsums, n_nodes);
        bscatter_kernel<<<EB, 1024, 0, stream>>>(src, dst, H, bcur, ebuf, n_edges);
        fill_local_kernel<<<NBUCK, 256, 0, stream>>>(ebuf, boff, off, cnt, srcs, n_nodes);
        agg_kernel<<<(n_nodes + 7) / 8, 256, 0, stream>>>(hwb, srcs, off, cnt, norm, bias,
                                                          out, n_nodes);
    } else {
        hipMemsetAsync(d_out, 0, (size_t)out_size * sizeof(float), stream);
        const int work = n_edges * D4;
        scatter_kernel<<<(work + 255) / 256, 256, 0, stream>>>(hwb, src, dst, out, n_edges);
        const int work2 = n_nodes * D4;
        finalize_kernel<<<(work2 + 255) / 256, 256, 0, stream>>>(out, norm, bias, n_nodes);
    }
}